// Round 2
// baseline (2463.739 us; speedup 1.0000x reference)
//
#include <hip/hip_runtime.h>
#include <hip/hip_bf16.h>
#include <math.h>

namespace {

constexpr int NB   = 16;     // graphs
constexpr int N1   = 4096;   // points per graph
constexpr int K1   = 1024;   // SA1 centers
constexpr int K2   = 256;    // SA2 centers
constexpr int MAXN = 32;     // max neighbors

__device__ __forceinline__ float sigmoidf_(float x) {
  return 1.0f / (1.0f + __expf(-x));
}

// ---------------- Farthest-point sampling ----------------
// One block (256 threads) per graph. Positions staged in LDS; per-thread
// min-distances live in registers. One __syncthreads per iteration via
// double-buffered partial-argmax slots.
template<int N, int NPT>
__global__ __launch_bounds__(256) void fps_kernel(
    const float* __restrict__ pos, int k, float* __restrict__ posd_out) {
  __shared__ float sx[N], sy[N], sz[N];
  __shared__ float redv[2][4];
  __shared__ int   redi[2][4];
  const int b = blockIdx.x;
  const int t = threadIdx.x;
  const int lane = t & 63, wave = t >> 6;
  const float* pb = pos + (size_t)b * N * 3;
  for (int p = t; p < N; p += 256) {
    sx[p] = pb[p * 3 + 0]; sy[p] = pb[p * 3 + 1]; sz[p] = pb[p * 3 + 2];
  }
  __syncthreads();
  float px[NPT], py[NPT], pz[NPT], mind[NPT];
  const float c0x = sx[0], c0y = sy[0], c0z = sz[0];
#pragma unroll
  for (int i = 0; i < NPT; i++) {
    const int p = i * 256 + t;
    px[i] = sx[p]; py[i] = sy[p]; pz[i] = sz[p];
    const float dx = px[i] - c0x, dy = py[i] - c0y, dz = pz[i] - c0z;
    mind[i] = dx * dx + dy * dy + dz * dz;
  }
  if (t == 0) {  // first selected point is index 0
    posd_out[(size_t)(b * k) * 3 + 0] = c0x;
    posd_out[(size_t)(b * k) * 3 + 1] = c0y;
    posd_out[(size_t)(b * k) * 3 + 2] = c0z;
  }
  for (int it = 1; it < k; it++) {
    // local argmax (tie -> smaller global index; local indices ascend)
    float bv = mind[0]; int bi = t;
#pragma unroll
    for (int i = 1; i < NPT; i++) {
      if (mind[i] > bv) { bv = mind[i]; bi = i * 256 + t; }
    }
#pragma unroll
    for (int off = 32; off; off >>= 1) {
      const float ov = __shfl_xor(bv, off);
      const int   oi = __shfl_xor(bi, off);
      if (ov > bv || (ov == bv && oi < bi)) { bv = ov; bi = oi; }
    }
    const int par = it & 1;
    if (lane == 0) { redv[par][wave] = bv; redi[par][wave] = bi; }
    __syncthreads();
    float wv = redv[par][0]; int wi = redi[par][0];
#pragma unroll
    for (int w = 1; w < 4; w++) {
      const float v2 = redv[par][w]; const int i2 = redi[par][w];
      if (v2 > wv || (v2 == wv && i2 < wi)) { wv = v2; wi = i2; }
    }
    const float nx = sx[wi], ny = sy[wi], nz = sz[wi];
    if (t == 0) {
      posd_out[(size_t)(b * k + it) * 3 + 0] = nx;
      posd_out[(size_t)(b * k + it) * 3 + 1] = ny;
      posd_out[(size_t)(b * k + it) * 3 + 2] = nz;
    }
#pragma unroll
    for (int i = 0; i < NPT; i++) {
      const float dx = px[i] - nx, dy = py[i] - ny, dz = pz[i] - nz;
      const float d2 = dx * dx + dy * dy + dz * dz;
      mind[i] = fminf(mind[i], d2);
    }
  }
}

// ---------------- radius + 32 nearest ----------------
// 4 waves per block, one center per wave. Candidates (d2, idx) appended to an
// LDS list via ballot compaction; if >32, extract the 32 smallest by
// (d2, idx) lexicographic order (matches lax.top_k stability).
template<int N, int CAP>
__global__ __launch_bounds__(256) void radius_nbr_kernel(
    const float* __restrict__ pts, const float* __restrict__ ctr,
    int K, float r2, int* __restrict__ nbr, int* __restrict__ cnt_out) {
  __shared__ float sx[N], sy[N], sz[N];
  __shared__ float candd[4][CAP];
  __shared__ int   candi[4][CAP];
  const int t = threadIdx.x;
  const int lane = t & 63, wave = t >> 6;
  const int bpg = K / 4;
  const int b = blockIdx.x / bpg;
  const int ci = (blockIdx.x % bpg) * 4 + wave;
  const float* pb = pts + (size_t)b * N * 3;
  for (int p = t; p < N; p += 256) {
    sx[p] = pb[p * 3 + 0]; sy[p] = pb[p * 3 + 1]; sz[p] = pb[p * 3 + 2];
  }
  __syncthreads();
  const size_t cbase = ((size_t)b * K + ci) * 3;
  const float cx = ctr[cbase + 0], cy = ctr[cbase + 1], cz = ctr[cbase + 2];
  int total = 0;
  for (int base = 0; base < N; base += 64) {
    const int p = base + lane;
    const float dx = sx[p] - cx, dy = sy[p] - cy, dz = sz[p] - cz;
    const float d2 = dx * dx + dy * dy + dz * dz;
    const bool pred = d2 <= r2;
    const unsigned long long m = __ballot(pred);
    if (pred) {
      const int slot = total + __popcll(m & ((1ull << lane) - 1ull));
      if (slot < CAP) { candd[wave][slot] = d2; candi[wave][slot] = p; }
    }
    total += __popcll(m);
  }
  if (total > CAP) total = CAP;  // unreachable for this data (Poisson ~17/34)
  int* nbp = nbr + ((size_t)b * K + ci) * MAXN;
  if (total <= MAXN) {
    if (lane < total) nbp[lane] = candi[wave][lane];
  } else {
    for (int jj = 0; jj < MAXN; jj++) {
      float bvd = INFINITY; int bvi = 0x7fffffff; int bslot = 0;
      for (int s = lane; s < total; s += 64) {
        const float d = candd[wave][s];
        const int i = candi[wave][s];
        if (d < bvd || (d == bvd && i < bvi)) { bvd = d; bvi = i; bslot = s; }
      }
#pragma unroll
      for (int off = 32; off; off >>= 1) {
        const float od = __shfl_xor(bvd, off);
        const int   oi = __shfl_xor(bvi, off);
        const int   os = __shfl_xor(bslot, off);
        if (od < bvd || (od == bvd && oi < bvi)) { bvd = od; bvi = oi; bslot = os; }
      }
      if (lane == 0) { nbp[jj] = bvi; candd[wave][bslot] = INFINITY; }
    }
  }
  if (lane == 0) cnt_out[(size_t)b * K + ci] = (total < MAXN) ? total : MAXN;
}

// ---------------- PointNetConv edge MLP + max aggregation ----------------
// One block per center. feat[j][FIN] and h1[j][H] staged in LDS.
template<int CIN_T, int H, int COUT, bool SCALE>
__global__ __launch_bounds__(256) void sa_conv_kernel(
    const float* __restrict__ xin, const float* __restrict__ pts,
    const float* __restrict__ ctr, const int* __restrict__ nbr,
    const int* __restrict__ cnt,
    const float* __restrict__ w1, const float* __restrict__ b1,
    const float* __restrict__ w2, const float* __restrict__ b2,
    const float* __restrict__ smean, const float* __restrict__ sstd,
    int N, int K, float* __restrict__ xout) {
  constexpr int FIN = CIN_T + 3;
  __shared__ float feat[MAXN * FIN];
  __shared__ __align__(16) float h1s[MAXN * H];
  __shared__ float part[2 * COUT];
  const int t = threadIdx.x;
  const int bk = blockIdx.x;          // b*K + center
  const int b = bk / K;
  const int V = cnt[bk];              // valid neighbor count (>=1: self)
  const int* nb = nbr + (size_t)bk * MAXN;
  const float ctrx = ctr[(size_t)bk * 3 + 0];
  const float ctry = ctr[(size_t)bk * 3 + 1];
  const float ctrz = ctr[(size_t)bk * 3 + 2];
  for (int item = t; item < V * FIN; item += 256) {
    const int j = item / FIN;
    const int f = item - j * FIN;
    const int p = nb[j];
    float v;
    if (f < CIN_T) {
      v = xin[((size_t)b * N + p) * CIN_T + f];
      if constexpr (SCALE) v = (v - smean[f]) / sstd[f];
    } else {
      const int d = f - CIN_T;
      const float pv = pts[((size_t)b * N + p) * 3 + d];
      v = pv - (d == 0 ? ctrx : (d == 1 ? ctry : ctrz));
    }
    feat[j * FIN + f] = v;
  }
  __syncthreads();
  {  // layer 1: h1[j][h] = sigmoid(feat[j]·W1[:,h] + b1[h])
    constexpr int JG = 256 / H;
    constexpr int JPT = MAXN / JG;
    const int h = t % H;
    const int jg = t / H;
    float acc[JPT];
#pragma unroll
    for (int i = 0; i < JPT; i++) acc[i] = 0.0f;
    for (int f = 0; f < FIN; f++) {
      const float w = w1[f * H + h];
#pragma unroll
      for (int i = 0; i < JPT; i++)
        acc[i] = fmaf(feat[(jg * JPT + i) * FIN + f], w, acc[i]);
    }
    const float bb = b1[h];
#pragma unroll
    for (int i = 0; i < JPT; i++) {
      const int j = jg * JPT + i;
      if (j < V) h1s[j * H + h] = sigmoidf_(acc[i] + bb);
    }
  }
  __syncthreads();
  {  // layer 2 + max over valid neighbors + bias + relu
    constexpr int CG = 256 / COUT;
    constexpr int JPT = MAXN / CG;
    const int c = t % COUT;
    const int cg = t / COUT;
    float acc[JPT];
#pragma unroll
    for (int i = 0; i < JPT; i++) acc[i] = 0.0f;
    for (int hq = 0; hq < H / 4; hq++) {
      const float w0 = w2[(hq * 4 + 0) * COUT + c];
      const float w1v = w2[(hq * 4 + 1) * COUT + c];
      const float w2v = w2[(hq * 4 + 2) * COUT + c];
      const float w3v = w2[(hq * 4 + 3) * COUT + c];
#pragma unroll
      for (int i = 0; i < JPT; i++) {
        const float4 hv =
            *reinterpret_cast<const float4*>(&h1s[(cg * JPT + i) * H + hq * 4]);
        acc[i] = fmaf(hv.x, w0, acc[i]);
        acc[i] = fmaf(hv.y, w1v, acc[i]);
        acc[i] = fmaf(hv.z, w2v, acc[i]);
        acc[i] = fmaf(hv.w, w3v, acc[i]);
      }
    }
    float m = -INFINITY;
#pragma unroll
    for (int i = 0; i < JPT; i++) {
      if (cg * JPT + i < V) m = fmaxf(m, acc[i]);
    }
    if constexpr (CG == 2) {
      part[cg * COUT + c] = m;
      __syncthreads();
      if (t < COUT) {
        const float mm = fmaxf(part[c], part[COUT + c]);
        const float o = mm + b2[c];
        xout[(size_t)bk * COUT + c] = o > 0.0f ? o : 0.0f;
      }
    } else {
      const float o = m + b2[c];
      xout[(size_t)bk * COUT + c] = o > 0.0f ? o : 0.0f;
    }
  }
}

// ---------------- Global SA: MLP(259->256->512) + relu + max pool ----------
__global__ __launch_bounds__(256) void global_sa_kernel(
    const float* __restrict__ x2, const float* __restrict__ posd2,
    const float* __restrict__ gw1, const float* __restrict__ gb1,
    const float* __restrict__ gw2, const float* __restrict__ gb2,
    unsigned int* __restrict__ gout) {  // [B][512] as float bits (relu >= 0)
  __shared__ float fin[4][259];
  __shared__ float s[4][256];
  const int t = threadIdx.x;
  const int blk = blockIdx.x;
  const int b = blk / 64;
  const int p0 = (blk % 64) * 4;
  for (int item = t; item < 4 * 259; item += 256) {
    const int p = item / 259, f = item - p * 259;
    const float v = (f < 256)
        ? x2[((size_t)b * 256 + p0 + p) * 256 + f]
        : posd2[((size_t)b * 256 + p0 + p) * 3 + (f - 256)];
    fin[p][f] = v;
  }
  __syncthreads();
  float acc[4] = {0.f, 0.f, 0.f, 0.f};
  for (int f = 0; f < 259; f++) {
    const float w = gw1[f * 256 + t];
#pragma unroll
    for (int p = 0; p < 4; p++) acc[p] = fmaf(fin[p][f], w, acc[p]);
  }
  const float bb = gb1[t];
#pragma unroll
  for (int p = 0; p < 4; p++) s[p][t] = sigmoidf_(acc[p] + bb);
  __syncthreads();
  float a0[4] = {0.f, 0.f, 0.f, 0.f}, a1[4] = {0.f, 0.f, 0.f, 0.f};
  for (int h = 0; h < 256; h++) {
    const float w0 = gw2[h * 512 + t];
    const float w1v = gw2[h * 512 + t + 256];
#pragma unroll
    for (int p = 0; p < 4; p++) {
      a0[p] = fmaf(s[p][h], w0, a0[p]);
      a1[p] = fmaf(s[p][h], w1v, a1[p]);
    }
  }
  const float b0 = gb2[t], b1v = gb2[t + 256];
  float m0 = 0.0f, m1 = 0.0f;  // relu floor
#pragma unroll
  for (int p = 0; p < 4; p++) {
    m0 = fmaxf(m0, fmaxf(a0[p] + b0, 0.0f));
    m1 = fmaxf(m1, fmaxf(a1[p] + b1v, 0.0f));
  }
  atomicMax(&gout[b * 512 + t], __float_as_uint(m0));
  atomicMax(&gout[b * 512 + t + 256], __float_as_uint(m1));
}

// ---------------- Final FC head (float32 output) ----------------
__global__ __launch_bounds__(256) void fc_kernel(
    const unsigned int* __restrict__ g,
    const float* __restrict__ fw1, const float* __restrict__ fb1,
    const float* __restrict__ fw2, const float* __restrict__ fb2,
    float* __restrict__ out) {
  __shared__ float gv[512];
  __shared__ float s[256];
  const int b = blockIdx.x, t = threadIdx.x;
  gv[t] = __uint_as_float(g[b * 512 + t]);
  gv[t + 256] = __uint_as_float(g[b * 512 + t + 256]);
  __syncthreads();
  float acc = 0.0f;
  for (int h = 0; h < 512; h++) acc = fmaf(gv[h], fw1[h * 256 + t], acc);
  s[t] = sigmoidf_(acc + fb1[t]);
  __syncthreads();
  if (t < 128) {
    float a2 = 0.0f;
    for (int h = 0; h < 256; h++) a2 = fmaf(s[h], fw2[h * 128 + t], a2);
    const float o = a2 + fb2[t];
    out[b * 128 + t] = o > 0.0f ? o : 0.0f;
  }
}

}  // namespace

extern "C" void kernel_launch(void* const* d_in, const int* in_sizes, int n_in,
                              void* d_out, int out_size, void* d_ws, size_t ws_size,
                              hipStream_t stream) {
  (void)in_sizes; (void)n_in; (void)out_size; (void)ws_size;
  const float* x     = (const float*)d_in[0];
  const float* pos   = (const float*)d_in[1];
  // d_in[2] = batch (int64) — sorted, equal-sized graphs, unused
  const float* smean = (const float*)d_in[3];
  const float* sstd  = (const float*)d_in[4];
  const float* s1w1  = (const float*)d_in[5];
  const float* s1b1  = (const float*)d_in[6];
  const float* s1w2  = (const float*)d_in[7];
  const float* s1b2  = (const float*)d_in[8];
  const float* s2w1  = (const float*)d_in[9];
  const float* s2b1  = (const float*)d_in[10];
  const float* s2w2  = (const float*)d_in[11];
  const float* s2b2  = (const float*)d_in[12];
  const float* gw1   = (const float*)d_in[13];
  const float* gb1   = (const float*)d_in[14];
  const float* gw2   = (const float*)d_in[15];
  const float* gb2   = (const float*)d_in[16];
  const float* fw1   = (const float*)d_in[17];
  const float* fb1   = (const float*)d_in[18];
  const float* fw2   = (const float*)d_in[19];
  const float* fb2   = (const float*)d_in[20];

  char* ws = (char*)d_ws;
  size_t off = 0;
  auto take = [&](size_t bytes) -> char* {
    char* p = ws + off;
    off = (off + bytes + 255) & ~(size_t)255;
    return p;
  };
  float* posd1       = (float*)take((size_t)NB * K1 * 3 * 4);
  int*   nbr1        = (int*)take((size_t)NB * K1 * MAXN * 4);
  int*   cnt1        = (int*)take((size_t)NB * K1 * 4);
  float* x1          = (float*)take((size_t)NB * K1 * 128 * 4);
  float* posd2       = (float*)take((size_t)NB * K2 * 3 * 4);
  int*   nbr2        = (int*)take((size_t)NB * K2 * MAXN * 4);
  int*   cnt2        = (int*)take((size_t)NB * K2 * 4);
  float* x2          = (float*)take((size_t)NB * K2 * 256 * 4);
  unsigned int* gbuf = (unsigned int*)take((size_t)NB * 512 * 4);

  hipMemsetAsync(gbuf, 0, (size_t)NB * 512 * 4, stream);

  hipLaunchKernelGGL((fps_kernel<N1, 16>), dim3(NB), dim3(256), 0, stream,
                     pos, K1, posd1);
  hipLaunchKernelGGL((radius_nbr_kernel<N1, 448>), dim3(NB * K1 / 4), dim3(256), 0, stream,
                     pos, posd1, K1, 4.0f, nbr1, cnt1);
  hipLaunchKernelGGL((sa_conv_kernel<32, 64, 128, true>), dim3(NB * K1), dim3(256), 0, stream,
                     x, pos, posd1, nbr1, cnt1, s1w1, s1b1, s1w2, s1b2,
                     smean, sstd, N1, K1, x1);
  hipLaunchKernelGGL((fps_kernel<K1, 4>), dim3(NB), dim3(256), 0, stream,
                     posd1, K2, posd2);
  hipLaunchKernelGGL((radius_nbr_kernel<K1, 448>), dim3(NB * K2 / 4), dim3(256), 0, stream,
                     posd1, posd2, K2, 16.0f, nbr2, cnt2);
  hipLaunchKernelGGL((sa_conv_kernel<128, 128, 256, false>), dim3(NB * K2), dim3(256), 0, stream,
                     x1, posd1, posd2, nbr2, cnt2, s2w1, s2b1, s2w2, s2b2,
                     nullptr, nullptr, K1, K2, x2);
  hipLaunchKernelGGL(global_sa_kernel, dim3(NB * 64), dim3(256), 0, stream,
                     x2, posd2, gw1, gb1, gw2, gb2, gbuf);
  hipLaunchKernelGGL(fc_kernel, dim3(NB), dim3(256), 0, stream,
                     gbuf, fw1, fb1, fw2, fb2, (float*)d_out);
}

// Round 3
// 1778.172 us; speedup vs baseline: 1.3855x; 1.3855x over previous
//
#include <hip/hip_runtime.h>
#include <hip/hip_bf16.h>
#include <math.h>

namespace {

constexpr int NB   = 16;     // graphs
constexpr int N1   = 4096;   // points per graph
constexpr int K1   = 1024;   // SA1 centers
constexpr int K2   = 256;    // SA2 centers
constexpr int MAXN = 32;     // max neighbors

__device__ __forceinline__ float sigmoidf_(float x) {
  return 1.0f / (1.0f + __expf(-x));
}

// ---------------- Farthest-point sampling (fused 2-level) ----------------
// One block (256 threads, 4 waves) per graph. Points staged in LDS, per-thread
// min-distances in registers. Per-iteration argmax: per-lane running best is
// packed as (f32 dist bits << 32) | ~point_idx so a single u64 max implements
// "max dist, tie -> smallest index" (matches jnp.argmax first-occurrence).
// Wave reduction via DPP (VALU latency) instead of ds_bpermute shuffles;
// cross-wave combine via one 8B LDS slot per wave + one barrier per iteration
// (ping-pong slots keep <2-iteration skew safe).

#define FPS_DPP_STEP(CTRL)                                                     \
  {                                                                            \
    const unsigned olo =                                                       \
        (unsigned)__builtin_amdgcn_update_dpp(0, (int)lo, (CTRL), 0xF, 0xF, true); \
    const unsigned ohi =                                                       \
        (unsigned)__builtin_amdgcn_update_dpp(0, (int)hi, (CTRL), 0xF, 0xF, true); \
    const unsigned long long o = ((unsigned long long)ohi << 32) | olo;        \
    const unsigned long long cur = ((unsigned long long)hi << 32) | lo;        \
    if (o > cur) { lo = olo; hi = ohi; }                                       \
  }

template<int NPT, bool SAVE_SEL>
__device__ __forceinline__ void fps_level(
    const float* __restrict__ sx, const float* __restrict__ sy,
    const float* __restrict__ sz, int k, float* __restrict__ posd,
    float* __restrict__ selx, float* __restrict__ sely, float* __restrict__ selz,
    unsigned long long (*red)[4]) {
  const int t = threadIdx.x;
  const int lane = t & 63, wave = t >> 6;
  float px[NPT], py[NPT], pz[NPT], mind[NPT];
  unsigned niv[NPT];
  const float c0x = sx[0], c0y = sy[0], c0z = sz[0];
  unsigned long long best = 0;  // identity: dist 0, idx ~0 (never wins)
#pragma unroll
  for (int i = 0; i < NPT; i++) {
    const int p = i * 256 + t;
    niv[i] = ~(unsigned)p;
    px[i] = sx[p]; py[i] = sy[p]; pz[i] = sz[p];
    const float dx = px[i] - c0x, dy = py[i] - c0y, dz = pz[i] - c0z;
    const float d2 = dx * dx + dy * dy + dz * dz;
    mind[i] = d2;
    const unsigned long long cand =
        ((unsigned long long)__float_as_uint(d2) << 32) | niv[i];
    if (cand > best) best = cand;
  }
  if (t == 0) {
    posd[0] = c0x; posd[1] = c0y; posd[2] = c0z;
    if (SAVE_SEL) { selx[0] = c0x; sely[0] = c0y; selz[0] = c0z; }
  }
  for (int it = 1; it < k; it++) {
    // ---- wave argmax via DPP: result lands in lane 63 ----
    unsigned lo = (unsigned)best, hi = (unsigned)(best >> 32);
    FPS_DPP_STEP(0x111)  // row_shr:1
    FPS_DPP_STEP(0x112)  // row_shr:2
    FPS_DPP_STEP(0x114)  // row_shr:4
    FPS_DPP_STEP(0x118)  // row_shr:8
    FPS_DPP_STEP(0x142)  // row_bcast:15
    FPS_DPP_STEP(0x143)  // row_bcast:31
    const unsigned bl = (unsigned)__builtin_amdgcn_readlane((int)lo, 63);
    const unsigned bh = (unsigned)__builtin_amdgcn_readlane((int)hi, 63);
    const int par = it & 1;
    if (lane == 0) red[par][wave] = ((unsigned long long)bh << 32) | bl;
    __syncthreads();
    const unsigned long long w0 = red[par][0], w1 = red[par][1];
    const unsigned long long w2 = red[par][2], w3 = red[par][3];
    const unsigned long long m01 = w0 > w1 ? w0 : w1;
    const unsigned long long m23 = w2 > w3 ? w2 : w3;
    const unsigned long long win = m01 > m23 ? m01 : m23;
    const int p = (int)(~(unsigned)win);
    const float nx = sx[p], ny = sy[p], nz = sz[p];
    if (t == 0) {
      posd[it * 3 + 0] = nx; posd[it * 3 + 1] = ny; posd[it * 3 + 2] = nz;
      if (SAVE_SEL) { selx[it] = nx; sely[it] = ny; selz[it] = nz; }
    }
    best = 0;
#pragma unroll
    for (int i = 0; i < NPT; i++) {
      const float dx = px[i] - nx, dy = py[i] - ny, dz = pz[i] - nz;
      const float d2 = dx * dx + dy * dy + dz * dz;
      const float m = fminf(mind[i], d2);
      mind[i] = m;
      const unsigned long long cand =
          ((unsigned long long)__float_as_uint(m) << 32) | niv[i];
      if (cand > best) best = cand;
    }
  }
}

#undef FPS_DPP_STEP

__global__ __launch_bounds__(256) void fps_fused_kernel(
    const float* __restrict__ pos, float* __restrict__ posd1,
    float* __restrict__ posd2) {
  __shared__ float sx[N1], sy[N1], sz[N1];
  __shared__ float s2x[K1], s2y[K1], s2z[K1];
  __shared__ __align__(16) unsigned long long red[2][4];
  const int b = blockIdx.x;
  const int t = threadIdx.x;
  const float* pb = pos + (size_t)b * N1 * 3;
  for (int p = t; p < N1; p += 256) {
    sx[p] = pb[p * 3 + 0]; sy[p] = pb[p * 3 + 1]; sz[p] = pb[p * 3 + 2];
  }
  __syncthreads();
  // level 1: 4096 -> 1024, staging selections into LDS for level 2
  fps_level<N1 / 256, true>(sx, sy, sz, K1, posd1 + (size_t)b * K1 * 3,
                            s2x, s2y, s2z, red);
  __syncthreads();
  // level 2: 1024 -> 256
  fps_level<K1 / 256, false>(s2x, s2y, s2z, K2, posd2 + (size_t)b * K2 * 3,
                             nullptr, nullptr, nullptr, red);
}

// ---------------- radius + 32 nearest ----------------
// 4 waves per block, one center per wave. Candidates (d2, idx) appended to an
// LDS list via ballot compaction; if >32, extract the 32 smallest by
// (d2, idx) lexicographic order (matches lax.top_k stability).
template<int N, int CAP>
__global__ __launch_bounds__(256) void radius_nbr_kernel(
    const float* __restrict__ pts, const float* __restrict__ ctr,
    int K, float r2, int* __restrict__ nbr, int* __restrict__ cnt_out) {
  __shared__ float sx[N], sy[N], sz[N];
  __shared__ float candd[4][CAP];
  __shared__ int   candi[4][CAP];
  const int t = threadIdx.x;
  const int lane = t & 63, wave = t >> 6;
  const int bpg = K / 4;
  const int b = blockIdx.x / bpg;
  const int ci = (blockIdx.x % bpg) * 4 + wave;
  const float* pb = pts + (size_t)b * N * 3;
  for (int p = t; p < N; p += 256) {
    sx[p] = pb[p * 3 + 0]; sy[p] = pb[p * 3 + 1]; sz[p] = pb[p * 3 + 2];
  }
  __syncthreads();
  const size_t cbase = ((size_t)b * K + ci) * 3;
  const float cx = ctr[cbase + 0], cy = ctr[cbase + 1], cz = ctr[cbase + 2];
  int total = 0;
  for (int base = 0; base < N; base += 64) {
    const int p = base + lane;
    const float dx = sx[p] - cx, dy = sy[p] - cy, dz = sz[p] - cz;
    const float d2 = dx * dx + dy * dy + dz * dz;
    const bool pred = d2 <= r2;
    const unsigned long long m = __ballot(pred);
    if (pred) {
      const int slot = total + __popcll(m & ((1ull << lane) - 1ull));
      if (slot < CAP) { candd[wave][slot] = d2; candi[wave][slot] = p; }
    }
    total += __popcll(m);
  }
  if (total > CAP) total = CAP;  // unreachable for this data (Poisson ~17/34)
  int* nbp = nbr + ((size_t)b * K + ci) * MAXN;
  if (total <= MAXN) {
    if (lane < total) nbp[lane] = candi[wave][lane];
  } else {
    for (int jj = 0; jj < MAXN; jj++) {
      float bvd = INFINITY; int bvi = 0x7fffffff; int bslot = 0;
      for (int s = lane; s < total; s += 64) {
        const float d = candd[wave][s];
        const int i = candi[wave][s];
        if (d < bvd || (d == bvd && i < bvi)) { bvd = d; bvi = i; bslot = s; }
      }
#pragma unroll
      for (int off = 32; off; off >>= 1) {
        const float od = __shfl_xor(bvd, off);
        const int   oi = __shfl_xor(bvi, off);
        const int   os = __shfl_xor(bslot, off);
        if (od < bvd || (od == bvd && oi < bvi)) { bvd = od; bvi = oi; bslot = os; }
      }
      if (lane == 0) { nbp[jj] = bvi; candd[wave][bslot] = INFINITY; }
    }
  }
  if (lane == 0) cnt_out[(size_t)b * K + ci] = (total < MAXN) ? total : MAXN;
}

// ---------------- PointNetConv edge MLP + max aggregation ----------------
// One block per center. feat[j][FIN] and h1[j][H] staged in LDS.
template<int CIN_T, int H, int COUT, bool SCALE>
__global__ __launch_bounds__(256) void sa_conv_kernel(
    const float* __restrict__ xin, const float* __restrict__ pts,
    const float* __restrict__ ctr, const int* __restrict__ nbr,
    const int* __restrict__ cnt,
    const float* __restrict__ w1, const float* __restrict__ b1,
    const float* __restrict__ w2, const float* __restrict__ b2,
    const float* __restrict__ smean, const float* __restrict__ sstd,
    int N, int K, float* __restrict__ xout) {
  constexpr int FIN = CIN_T + 3;
  __shared__ float feat[MAXN * FIN];
  __shared__ __align__(16) float h1s[MAXN * H];
  __shared__ float part[2 * COUT];
  const int t = threadIdx.x;
  const int bk = blockIdx.x;          // b*K + center
  const int b = bk / K;
  const int V = cnt[bk];              // valid neighbor count (>=1: self)
  const int* nb = nbr + (size_t)bk * MAXN;
  const float ctrx = ctr[(size_t)bk * 3 + 0];
  const float ctry = ctr[(size_t)bk * 3 + 1];
  const float ctrz = ctr[(size_t)bk * 3 + 2];
  for (int item = t; item < V * FIN; item += 256) {
    const int j = item / FIN;
    const int f = item - j * FIN;
    const int p = nb[j];
    float v;
    if (f < CIN_T) {
      v = xin[((size_t)b * N + p) * CIN_T + f];
      if constexpr (SCALE) v = (v - smean[f]) / sstd[f];
    } else {
      const int d = f - CIN_T;
      const float pv = pts[((size_t)b * N + p) * 3 + d];
      v = pv - (d == 0 ? ctrx : (d == 1 ? ctry : ctrz));
    }
    feat[j * FIN + f] = v;
  }
  __syncthreads();
  {  // layer 1: h1[j][h] = sigmoid(feat[j]·W1[:,h] + b1[h])
    constexpr int JG = 256 / H;
    constexpr int JPT = MAXN / JG;
    const int h = t % H;
    const int jg = t / H;
    float acc[JPT];
#pragma unroll
    for (int i = 0; i < JPT; i++) acc[i] = 0.0f;
    for (int f = 0; f < FIN; f++) {
      const float w = w1[f * H + h];
#pragma unroll
      for (int i = 0; i < JPT; i++)
        acc[i] = fmaf(feat[(jg * JPT + i) * FIN + f], w, acc[i]);
    }
    const float bb = b1[h];
#pragma unroll
    for (int i = 0; i < JPT; i++) {
      const int j = jg * JPT + i;
      if (j < V) h1s[j * H + h] = sigmoidf_(acc[i] + bb);
    }
  }
  __syncthreads();
  {  // layer 2 + max over valid neighbors + bias + relu
    constexpr int CG = 256 / COUT;
    constexpr int JPT = MAXN / CG;
    const int c = t % COUT;
    const int cg = t / COUT;
    float acc[JPT];
#pragma unroll
    for (int i = 0; i < JPT; i++) acc[i] = 0.0f;
    for (int hq = 0; hq < H / 4; hq++) {
      const float w0 = w2[(hq * 4 + 0) * COUT + c];
      const float w1v = w2[(hq * 4 + 1) * COUT + c];
      const float w2v = w2[(hq * 4 + 2) * COUT + c];
      const float w3v = w2[(hq * 4 + 3) * COUT + c];
#pragma unroll
      for (int i = 0; i < JPT; i++) {
        const float4 hv =
            *reinterpret_cast<const float4*>(&h1s[(cg * JPT + i) * H + hq * 4]);
        acc[i] = fmaf(hv.x, w0, acc[i]);
        acc[i] = fmaf(hv.y, w1v, acc[i]);
        acc[i] = fmaf(hv.z, w2v, acc[i]);
        acc[i] = fmaf(hv.w, w3v, acc[i]);
      }
    }
    float m = -INFINITY;
#pragma unroll
    for (int i = 0; i < JPT; i++) {
      if (cg * JPT + i < V) m = fmaxf(m, acc[i]);
    }
    if constexpr (CG == 2) {
      part[cg * COUT + c] = m;
      __syncthreads();
      if (t < COUT) {
        const float mm = fmaxf(part[c], part[COUT + c]);
        const float o = mm + b2[c];
        xout[(size_t)bk * COUT + c] = o > 0.0f ? o : 0.0f;
      }
    } else {
      const float o = m + b2[c];
      xout[(size_t)bk * COUT + c] = o > 0.0f ? o : 0.0f;
    }
  }
}

// ---------------- Global SA: MLP(259->256->512) + relu + max pool ----------
__global__ __launch_bounds__(256) void global_sa_kernel(
    const float* __restrict__ x2, const float* __restrict__ posd2,
    const float* __restrict__ gw1, const float* __restrict__ gb1,
    const float* __restrict__ gw2, const float* __restrict__ gb2,
    unsigned int* __restrict__ gout) {  // [B][512] as float bits (relu >= 0)
  __shared__ float fin[4][259];
  __shared__ float s[4][256];
  const int t = threadIdx.x;
  const int blk = blockIdx.x;
  const int b = blk / 64;
  const int p0 = (blk % 64) * 4;
  for (int item = t; item < 4 * 259; item += 256) {
    const int p = item / 259, f = item - p * 259;
    const float v = (f < 256)
        ? x2[((size_t)b * 256 + p0 + p) * 256 + f]
        : posd2[((size_t)b * 256 + p0 + p) * 3 + (f - 256)];
    fin[p][f] = v;
  }
  __syncthreads();
  float acc[4] = {0.f, 0.f, 0.f, 0.f};
  for (int f = 0; f < 259; f++) {
    const float w = gw1[f * 256 + t];
#pragma unroll
    for (int p = 0; p < 4; p++) acc[p] = fmaf(fin[p][f], w, acc[p]);
  }
  const float bb = gb1[t];
#pragma unroll
  for (int p = 0; p < 4; p++) s[p][t] = sigmoidf_(acc[p] + bb);
  __syncthreads();
  float a0[4] = {0.f, 0.f, 0.f, 0.f}, a1[4] = {0.f, 0.f, 0.f, 0.f};
  for (int h = 0; h < 256; h++) {
    const float w0 = gw2[h * 512 + t];
    const float w1v = gw2[h * 512 + t + 256];
#pragma unroll
    for (int p = 0; p < 4; p++) {
      a0[p] = fmaf(s[p][h], w0, a0[p]);
      a1[p] = fmaf(s[p][h], w1v, a1[p]);
    }
  }
  const float b0 = gb2[t], b1v = gb2[t + 256];
  float m0 = 0.0f, m1 = 0.0f;  // relu floor
#pragma unroll
  for (int p = 0; p < 4; p++) {
    m0 = fmaxf(m0, fmaxf(a0[p] + b0, 0.0f));
    m1 = fmaxf(m1, fmaxf(a1[p] + b1v, 0.0f));
  }
  atomicMax(&gout[b * 512 + t], __float_as_uint(m0));
  atomicMax(&gout[b * 512 + t + 256], __float_as_uint(m1));
}

// ---------------- Final FC head (float32 output) ----------------
__global__ __launch_bounds__(256) void fc_kernel(
    const unsigned int* __restrict__ g,
    const float* __restrict__ fw1, const float* __restrict__ fb1,
    const float* __restrict__ fw2, const float* __restrict__ fb2,
    float* __restrict__ out) {
  __shared__ float gv[512];
  __shared__ float s[256];
  const int b = blockIdx.x, t = threadIdx.x;
  gv[t] = __uint_as_float(g[b * 512 + t]);
  gv[t + 256] = __uint_as_float(g[b * 512 + t + 256]);
  __syncthreads();
  float acc = 0.0f;
  for (int h = 0; h < 512; h++) acc = fmaf(gv[h], fw1[h * 256 + t], acc);
  s[t] = sigmoidf_(acc + fb1[t]);
  __syncthreads();
  if (t < 128) {
    float a2 = 0.0f;
    for (int h = 0; h < 256; h++) a2 = fmaf(s[h], fw2[h * 128 + t], a2);
    const float o = a2 + fb2[t];
    out[b * 128 + t] = o > 0.0f ? o : 0.0f;
  }
}

}  // namespace

extern "C" void kernel_launch(void* const* d_in, const int* in_sizes, int n_in,
                              void* d_out, int out_size, void* d_ws, size_t ws_size,
                              hipStream_t stream) {
  (void)in_sizes; (void)n_in; (void)out_size; (void)ws_size;
  const float* x     = (const float*)d_in[0];
  const float* pos   = (const float*)d_in[1];
  // d_in[2] = batch (int64) — sorted, equal-sized graphs, unused
  const float* smean = (const float*)d_in[3];
  const float* sstd  = (const float*)d_in[4];
  const float* s1w1  = (const float*)d_in[5];
  const float* s1b1  = (const float*)d_in[6];
  const float* s1w2  = (const float*)d_in[7];
  const float* s1b2  = (const float*)d_in[8];
  const float* s2w1  = (const float*)d_in[9];
  const float* s2b1  = (const float*)d_in[10];
  const float* s2w2  = (const float*)d_in[11];
  const float* s2b2  = (const float*)d_in[12];
  const float* gw1   = (const float*)d_in[13];
  const float* gb1   = (const float*)d_in[14];
  const float* gw2   = (const float*)d_in[15];
  const float* gb2   = (const float*)d_in[16];
  const float* fw1   = (const float*)d_in[17];
  const float* fb1   = (const float*)d_in[18];
  const float* fw2   = (const float*)d_in[19];
  const float* fb2   = (const float*)d_in[20];

  char* ws = (char*)d_ws;
  size_t off = 0;
  auto take = [&](size_t bytes) -> char* {
    char* p = ws + off;
    off = (off + bytes + 255) & ~(size_t)255;
    return p;
  };
  float* posd1       = (float*)take((size_t)NB * K1 * 3 * 4);
  int*   nbr1        = (int*)take((size_t)NB * K1 * MAXN * 4);
  int*   cnt1        = (int*)take((size_t)NB * K1 * 4);
  float* x1          = (float*)take((size_t)NB * K1 * 128 * 4);
  float* posd2       = (float*)take((size_t)NB * K2 * 3 * 4);
  int*   nbr2        = (int*)take((size_t)NB * K2 * MAXN * 4);
  int*   cnt2        = (int*)take((size_t)NB * K2 * 4);
  float* x2          = (float*)take((size_t)NB * K2 * 256 * 4);
  unsigned int* gbuf = (unsigned int*)take((size_t)NB * 512 * 4);

  hipMemsetAsync(gbuf, 0, (size_t)NB * 512 * 4, stream);

  hipLaunchKernelGGL(fps_fused_kernel, dim3(NB), dim3(256), 0, stream,
                     pos, posd1, posd2);
  hipLaunchKernelGGL((radius_nbr_kernel<N1, 448>), dim3(NB * K1 / 4), dim3(256), 0, stream,
                     pos, posd1, K1, 4.0f, nbr1, cnt1);
  hipLaunchKernelGGL((sa_conv_kernel<32, 64, 128, true>), dim3(NB * K1), dim3(256), 0, stream,
                     x, pos, posd1, nbr1, cnt1, s1w1, s1b1, s1w2, s1b2,
                     smean, sstd, N1, K1, x1);
  hipLaunchKernelGGL((radius_nbr_kernel<K1, 448>), dim3(NB * K2 / 4), dim3(256), 0, stream,
                     posd1, posd2, K2, 16.0f, nbr2, cnt2);
  hipLaunchKernelGGL((sa_conv_kernel<128, 128, 256, false>), dim3(NB * K2), dim3(256), 0, stream,
                     x1, posd1, posd2, nbr2, cnt2, s2w1, s2b1, s2w2, s2b2,
                     nullptr, nullptr, K1, K2, x2);
  hipLaunchKernelGGL(global_sa_kernel, dim3(NB * 64), dim3(256), 0, stream,
                     x2, posd2, gw1, gb1, gw2, gb2, gbuf);
  hipLaunchKernelGGL(fc_kernel, dim3(NB), dim3(256), 0, stream,
                     gbuf, fw1, fb1, fw2, fb2, (float*)d_out);
}

// Round 4
// 1745.767 us; speedup vs baseline: 1.4113x; 1.0186x over previous
//
#include <hip/hip_runtime.h>
#include <hip/hip_bf16.h>
#include <math.h>

namespace {

constexpr int NB   = 16;     // graphs
constexpr int N1   = 4096;   // points per graph
constexpr int K1   = 1024;   // SA1 centers
constexpr int K2   = 256;    // SA2 centers
constexpr int MAXN = 32;     // max neighbors

__device__ __forceinline__ float sigmoidf_(float x) {
  return 1.0f / (1.0f + __expf(-x));
}

// ---------------- Farthest-point sampling (fused 2-level) ----------------
// One block (256 threads, 4 waves) per graph. Points staged in LDS, per-thread
// min-distances in registers. Per-iteration argmax: per-lane running best is
// packed as (f32 dist bits << 32) | ~point_idx so a single u64 max implements
// "max dist, tie -> smallest index" (matches jnp.argmax first-occurrence).
// Wave reduction via DPP; cross-wave combine via ping-pong LDS slots.
// NO global traffic inside the loop: selections are staged in LDS and
// bulk-written after both levels (the in-loop global store forced a
// vmcnt(0) drain at every barrier -> ~650 extra cycles/iteration).

#define FPS_DPP_STEP(CTRL)                                                     \
  {                                                                            \
    const unsigned olo =                                                       \
        (unsigned)__builtin_amdgcn_update_dpp(0, (int)lo, (CTRL), 0xF, 0xF, true); \
    const unsigned ohi =                                                       \
        (unsigned)__builtin_amdgcn_update_dpp(0, (int)hi, (CTRL), 0xF, 0xF, true); \
    const unsigned long long o = ((unsigned long long)ohi << 32) | olo;        \
    const unsigned long long cur = ((unsigned long long)hi << 32) | lo;        \
    if (o > cur) { lo = olo; hi = ohi; }                                       \
  }

template<int NPT>
__device__ __forceinline__ void fps_level(
    const float* __restrict__ sx, const float* __restrict__ sy,
    const float* __restrict__ sz, int k,
    float* __restrict__ selx, float* __restrict__ sely,
    float* __restrict__ selz,                       // LDS, length k
    unsigned long long (*red)[4]) {
  const int t = threadIdx.x;
  const int lane = t & 63, wave = t >> 6;
  float px[NPT], py[NPT], pz[NPT], mind[NPT];
  unsigned niv[NPT];
  const float c0x = sx[0], c0y = sy[0], c0z = sz[0];
  unsigned long long best = 0;  // identity: dist 0, idx ~0 (never wins)
#pragma unroll
  for (int i = 0; i < NPT; i++) {
    const int p = i * 256 + t;
    niv[i] = ~(unsigned)p;
    px[i] = sx[p]; py[i] = sy[p]; pz[i] = sz[p];
    const float dx = px[i] - c0x, dy = py[i] - c0y, dz = pz[i] - c0z;
    const float d2 = dx * dx + dy * dy + dz * dz;
    mind[i] = d2;
    const unsigned long long cand =
        ((unsigned long long)__float_as_uint(d2) << 32) | niv[i];
    if (cand > best) best = cand;
  }
  if (t == 0) { selx[0] = c0x; sely[0] = c0y; selz[0] = c0z; }
  for (int it = 1; it < k; it++) {
    // ---- wave argmax via DPP: result lands in lane 63 ----
    unsigned lo = (unsigned)best, hi = (unsigned)(best >> 32);
    FPS_DPP_STEP(0x111)  // row_shr:1
    FPS_DPP_STEP(0x112)  // row_shr:2
    FPS_DPP_STEP(0x114)  // row_shr:4
    FPS_DPP_STEP(0x118)  // row_shr:8
    FPS_DPP_STEP(0x142)  // row_bcast:15
    FPS_DPP_STEP(0x143)  // row_bcast:31
    const unsigned bl = (unsigned)__builtin_amdgcn_readlane((int)lo, 63);
    const unsigned bh = (unsigned)__builtin_amdgcn_readlane((int)hi, 63);
    const int par = it & 1;
    if (lane == 0) red[par][wave] = ((unsigned long long)bh << 32) | bl;
    __syncthreads();
    const unsigned long long w0 = red[par][0], w1 = red[par][1];
    const unsigned long long w2 = red[par][2], w3 = red[par][3];
    const unsigned long long m01 = w0 > w1 ? w0 : w1;
    const unsigned long long m23 = w2 > w3 ? w2 : w3;
    const unsigned long long win = m01 > m23 ? m01 : m23;
    const int p = (int)(~(unsigned)win);
    const float nx = sx[p], ny = sy[p], nz = sz[p];
    if (t == 0) { selx[it] = nx; sely[it] = ny; selz[it] = nz; }
    best = 0;
#pragma unroll
    for (int i = 0; i < NPT; i++) {
      const float dx = px[i] - nx, dy = py[i] - ny, dz = pz[i] - nz;
      const float d2 = dx * dx + dy * dy + dz * dz;
      const float m = fminf(mind[i], d2);
      mind[i] = m;
      const unsigned long long cand =
          ((unsigned long long)__float_as_uint(m) << 32) | niv[i];
      if (cand > best) best = cand;
    }
  }
}

#undef FPS_DPP_STEP

__global__ __launch_bounds__(256) void fps_fused_kernel(
    const float* __restrict__ pos, float* __restrict__ posd1,
    float* __restrict__ posd2) {
  __shared__ float sx[N1], sy[N1], sz[N1];       // 48 KiB
  __shared__ float s2x[K1], s2y[K1], s2z[K1];    // 12 KiB (level-1 selections)
  __shared__ float p2x[K2], p2y[K2], p2z[K2];    //  3 KiB (level-2 selections)
  __shared__ __align__(16) unsigned long long red[2][4];
  const int b = blockIdx.x;
  const int t = threadIdx.x;
  const float* pb = pos + (size_t)b * N1 * 3;
  for (int p = t; p < N1; p += 256) {
    sx[p] = pb[p * 3 + 0]; sy[p] = pb[p * 3 + 1]; sz[p] = pb[p * 3 + 2];
  }
  __syncthreads();
  // level 1: 4096 -> 1024 (selections -> s2*)
  fps_level<N1 / 256>(sx, sy, sz, K1, s2x, s2y, s2z, red);
  __syncthreads();
  // level 2: 1024 -> 256 (selections -> p2*)
  fps_level<K1 / 256>(s2x, s2y, s2z, K2, p2x, p2y, p2z, red);
  __syncthreads();
  // bulk write both center lists (coalesced-ish, once)
  float* o1 = posd1 + (size_t)b * K1 * 3;
  for (int i = t; i < K1; i += 256) {
    o1[i * 3 + 0] = s2x[i]; o1[i * 3 + 1] = s2y[i]; o1[i * 3 + 2] = s2z[i];
  }
  float* o2 = posd2 + (size_t)b * K2 * 3;
  for (int i = t; i < K2; i += 256) {
    o2[i * 3 + 0] = p2x[i]; o2[i * 3 + 1] = p2y[i]; o2[i * 3 + 2] = p2z[i];
  }
}

// ---------------- radius + 32 nearest ----------------
// 4 waves per block, one center per wave. Candidates (d2, idx) appended to an
// LDS list via ballot compaction; if >32, extract the 32 smallest by
// (d2, idx) lexicographic order (matches lax.top_k stability).
template<int N, int CAP>
__global__ __launch_bounds__(256) void radius_nbr_kernel(
    const float* __restrict__ pts, const float* __restrict__ ctr,
    int K, float r2, int* __restrict__ nbr, int* __restrict__ cnt_out) {
  __shared__ float sx[N], sy[N], sz[N];
  __shared__ float candd[4][CAP];
  __shared__ int   candi[4][CAP];
  const int t = threadIdx.x;
  const int lane = t & 63, wave = t >> 6;
  const int bpg = K / 4;
  const int b = blockIdx.x / bpg;
  const int ci = (blockIdx.x % bpg) * 4 + wave;
  const float* pb = pts + (size_t)b * N * 3;
  for (int p = t; p < N; p += 256) {
    sx[p] = pb[p * 3 + 0]; sy[p] = pb[p * 3 + 1]; sz[p] = pb[p * 3 + 2];
  }
  __syncthreads();
  const size_t cbase = ((size_t)b * K + ci) * 3;
  const float cx = ctr[cbase + 0], cy = ctr[cbase + 1], cz = ctr[cbase + 2];
  int total = 0;
  for (int base = 0; base < N; base += 64) {
    const int p = base + lane;
    const float dx = sx[p] - cx, dy = sy[p] - cy, dz = sz[p] - cz;
    const float d2 = dx * dx + dy * dy + dz * dz;
    const bool pred = d2 <= r2;
    const unsigned long long m = __ballot(pred);
    if (pred) {
      const int slot = total + __popcll(m & ((1ull << lane) - 1ull));
      if (slot < CAP) { candd[wave][slot] = d2; candi[wave][slot] = p; }
    }
    total += __popcll(m);
  }
  if (total > CAP) total = CAP;  // unreachable for this data (Poisson ~17/34)
  int* nbp = nbr + ((size_t)b * K + ci) * MAXN;
  if (total <= MAXN) {
    if (lane < total) nbp[lane] = candi[wave][lane];
  } else {
    for (int jj = 0; jj < MAXN; jj++) {
      float bvd = INFINITY; int bvi = 0x7fffffff; int bslot = 0;
      for (int s = lane; s < total; s += 64) {
        const float d = candd[wave][s];
        const int i = candi[wave][s];
        if (d < bvd || (d == bvd && i < bvi)) { bvd = d; bvi = i; bslot = s; }
      }
#pragma unroll
      for (int off = 32; off; off >>= 1) {
        const float od = __shfl_xor(bvd, off);
        const int   oi = __shfl_xor(bvi, off);
        const int   os = __shfl_xor(bslot, off);
        if (od < bvd || (od == bvd && oi < bvi)) { bvd = od; bvi = oi; bslot = os; }
      }
      if (lane == 0) { nbp[jj] = bvi; candd[wave][bslot] = INFINITY; }
    }
  }
  if (lane == 0) cnt_out[(size_t)b * K + ci] = (total < MAXN) ? total : MAXN;
}

// ---------------- PointNetConv edge MLP + max aggregation ----------------
// One block per center. feat[j][FIN] and h1[j][H] staged in LDS.
template<int CIN_T, int H, int COUT, bool SCALE>
__global__ __launch_bounds__(256) void sa_conv_kernel(
    const float* __restrict__ xin, const float* __restrict__ pts,
    const float* __restrict__ ctr, const int* __restrict__ nbr,
    const int* __restrict__ cnt,
    const float* __restrict__ w1, const float* __restrict__ b1,
    const float* __restrict__ w2, const float* __restrict__ b2,
    const float* __restrict__ smean, const float* __restrict__ sstd,
    int N, int K, float* __restrict__ xout) {
  constexpr int FIN = CIN_T + 3;
  __shared__ float feat[MAXN * FIN];
  __shared__ __align__(16) float h1s[MAXN * H];
  __shared__ float part[2 * COUT];
  const int t = threadIdx.x;
  const int bk = blockIdx.x;          // b*K + center
  const int b = bk / K;
  const int V = cnt[bk];              // valid neighbor count (>=1: self)
  const int* nb = nbr + (size_t)bk * MAXN;
  const float ctrx = ctr[(size_t)bk * 3 + 0];
  const float ctry = ctr[(size_t)bk * 3 + 1];
  const float ctrz = ctr[(size_t)bk * 3 + 2];
  for (int item = t; item < V * FIN; item += 256) {
    const int j = item / FIN;
    const int f = item - j * FIN;
    const int p = nb[j];
    float v;
    if (f < CIN_T) {
      v = xin[((size_t)b * N + p) * CIN_T + f];
      if constexpr (SCALE) v = (v - smean[f]) / sstd[f];
    } else {
      const int d = f - CIN_T;
      const float pv = pts[((size_t)b * N + p) * 3 + d];
      v = pv - (d == 0 ? ctrx : (d == 1 ? ctry : ctrz));
    }
    feat[j * FIN + f] = v;
  }
  __syncthreads();
  {  // layer 1: h1[j][h] = sigmoid(feat[j]·W1[:,h] + b1[h])
    constexpr int JG = 256 / H;
    constexpr int JPT = MAXN / JG;
    const int h = t % H;
    const int jg = t / H;
    float acc[JPT];
#pragma unroll
    for (int i = 0; i < JPT; i++) acc[i] = 0.0f;
    for (int f = 0; f < FIN; f++) {
      const float w = w1[f * H + h];
#pragma unroll
      for (int i = 0; i < JPT; i++)
        acc[i] = fmaf(feat[(jg * JPT + i) * FIN + f], w, acc[i]);
    }
    const float bb = b1[h];
#pragma unroll
    for (int i = 0; i < JPT; i++) {
      const int j = jg * JPT + i;
      if (j < V) h1s[j * H + h] = sigmoidf_(acc[i] + bb);
    }
  }
  __syncthreads();
  {  // layer 2 + max over valid neighbors + bias + relu
    constexpr int CG = 256 / COUT;
    constexpr int JPT = MAXN / CG;
    const int c = t % COUT;
    const int cg = t / COUT;
    float acc[JPT];
#pragma unroll
    for (int i = 0; i < JPT; i++) acc[i] = 0.0f;
    for (int hq = 0; hq < H / 4; hq++) {
      const float w0 = w2[(hq * 4 + 0) * COUT + c];
      const float w1v = w2[(hq * 4 + 1) * COUT + c];
      const float w2v = w2[(hq * 4 + 2) * COUT + c];
      const float w3v = w2[(hq * 4 + 3) * COUT + c];
#pragma unroll
      for (int i = 0; i < JPT; i++) {
        const float4 hv =
            *reinterpret_cast<const float4*>(&h1s[(cg * JPT + i) * H + hq * 4]);
        acc[i] = fmaf(hv.x, w0, acc[i]);
        acc[i] = fmaf(hv.y, w1v, acc[i]);
        acc[i] = fmaf(hv.z, w2v, acc[i]);
        acc[i] = fmaf(hv.w, w3v, acc[i]);
      }
    }
    float m = -INFINITY;
#pragma unroll
    for (int i = 0; i < JPT; i++) {
      if (cg * JPT + i < V) m = fmaxf(m, acc[i]);
    }
    if constexpr (CG == 2) {
      part[cg * COUT + c] = m;
      __syncthreads();
      if (t < COUT) {
        const float mm = fmaxf(part[c], part[COUT + c]);
        const float o = mm + b2[c];
        xout[(size_t)bk * COUT + c] = o > 0.0f ? o : 0.0f;
      }
    } else {
      const float o = m + b2[c];
      xout[(size_t)bk * COUT + c] = o > 0.0f ? o : 0.0f;
    }
  }
}

// ---------------- Global SA: MLP(259->256->512) + relu + max pool ----------
__global__ __launch_bounds__(256) void global_sa_kernel(
    const float* __restrict__ x2, const float* __restrict__ posd2,
    const float* __restrict__ gw1, const float* __restrict__ gb1,
    const float* __restrict__ gw2, const float* __restrict__ gb2,
    unsigned int* __restrict__ gout) {  // [B][512] as float bits (relu >= 0)
  __shared__ float fin[4][259];
  __shared__ float s[4][256];
  const int t = threadIdx.x;
  const int blk = blockIdx.x;
  const int b = blk / 64;
  const int p0 = (blk % 64) * 4;
  for (int item = t; item < 4 * 259; item += 256) {
    const int p = item / 259, f = item - p * 259;
    const float v = (f < 256)
        ? x2[((size_t)b * 256 + p0 + p) * 256 + f]
        : posd2[((size_t)b * 256 + p0 + p) * 3 + (f - 256)];
    fin[p][f] = v;
  }
  __syncthreads();
  float acc[4] = {0.f, 0.f, 0.f, 0.f};
  for (int f = 0; f < 259; f++) {
    const float w = gw1[f * 256 + t];
#pragma unroll
    for (int p = 0; p < 4; p++) acc[p] = fmaf(fin[p][f], w, acc[p]);
  }
  const float bb = gb1[t];
#pragma unroll
  for (int p = 0; p < 4; p++) s[p][t] = sigmoidf_(acc[p] + bb);
  __syncthreads();
  float a0[4] = {0.f, 0.f, 0.f, 0.f}, a1[4] = {0.f, 0.f, 0.f, 0.f};
  for (int h = 0; h < 256; h++) {
    const float w0 = gw2[h * 512 + t];
    const float w1v = gw2[h * 512 + t + 256];
#pragma unroll
    for (int p = 0; p < 4; p++) {
      a0[p] = fmaf(s[p][h], w0, a0[p]);
      a1[p] = fmaf(s[p][h], w1v, a1[p]);
    }
  }
  const float b0 = gb2[t], b1v = gb2[t + 256];
  float m0 = 0.0f, m1 = 0.0f;  // relu floor
#pragma unroll
  for (int p = 0; p < 4; p++) {
    m0 = fmaxf(m0, fmaxf(a0[p] + b0, 0.0f));
    m1 = fmaxf(m1, fmaxf(a1[p] + b1v, 0.0f));
  }
  atomicMax(&gout[b * 512 + t], __float_as_uint(m0));
  atomicMax(&gout[b * 512 + t + 256], __float_as_uint(m1));
}

// ---------------- Final FC head (float32 output) ----------------
__global__ __launch_bounds__(256) void fc_kernel(
    const unsigned int* __restrict__ g,
    const float* __restrict__ fw1, const float* __restrict__ fb1,
    const float* __restrict__ fw2, const float* __restrict__ fb2,
    float* __restrict__ out) {
  __shared__ float gv[512];
  __shared__ float s[256];
  const int b = blockIdx.x, t = threadIdx.x;
  gv[t] = __uint_as_float(g[b * 512 + t]);
  gv[t + 256] = __uint_as_float(g[b * 512 + t + 256]);
  __syncthreads();
  float acc = 0.0f;
  for (int h = 0; h < 512; h++) acc = fmaf(gv[h], fw1[h * 256 + t], acc);
  s[t] = sigmoidf_(acc + fb1[t]);
  __syncthreads();
  if (t < 128) {
    float a2 = 0.0f;
    for (int h = 0; h < 256; h++) a2 = fmaf(s[h], fw2[h * 128 + t], a2);
    const float o = a2 + fb2[t];
    out[b * 128 + t] = o > 0.0f ? o : 0.0f;
  }
}

}  // namespace

extern "C" void kernel_launch(void* const* d_in, const int* in_sizes, int n_in,
                              void* d_out, int out_size, void* d_ws, size_t ws_size,
                              hipStream_t stream) {
  (void)in_sizes; (void)n_in; (void)out_size; (void)ws_size;
  const float* x     = (const float*)d_in[0];
  const float* pos   = (const float*)d_in[1];
  // d_in[2] = batch (int64) — sorted, equal-sized graphs, unused
  const float* smean = (const float*)d_in[3];
  const float* sstd  = (const float*)d_in[4];
  const float* s1w1  = (const float*)d_in[5];
  const float* s1b1  = (const float*)d_in[6];
  const float* s1w2  = (const float*)d_in[7];
  const float* s1b2  = (const float*)d_in[8];
  const float* s2w1  = (const float*)d_in[9];
  const float* s2b1  = (const float*)d_in[10];
  const float* s2w2  = (const float*)d_in[11];
  const float* s2b2  = (const float*)d_in[12];
  const float* gw1   = (const float*)d_in[13];
  const float* gb1   = (const float*)d_in[14];
  const float* gw2   = (const float*)d_in[15];
  const float* gb2   = (const float*)d_in[16];
  const float* fw1   = (const float*)d_in[17];
  const float* fb1   = (const float*)d_in[18];
  const float* fw2   = (const float*)d_in[19];
  const float* fb2   = (const float*)d_in[20];

  char* ws = (char*)d_ws;
  size_t off = 0;
  auto take = [&](size_t bytes) -> char* {
    char* p = ws + off;
    off = (off + bytes + 255) & ~(size_t)255;
    return p;
  };
  float* posd1       = (float*)take((size_t)NB * K1 * 3 * 4);
  int*   nbr1        = (int*)take((size_t)NB * K1 * MAXN * 4);
  int*   cnt1        = (int*)take((size_t)NB * K1 * 4);
  float* x1          = (float*)take((size_t)NB * K1 * 128 * 4);
  float* posd2       = (float*)take((size_t)NB * K2 * 3 * 4);
  int*   nbr2        = (int*)take((size_t)NB * K2 * MAXN * 4);
  int*   cnt2        = (int*)take((size_t)NB * K2 * 4);
  float* x2          = (float*)take((size_t)NB * K2 * 256 * 4);
  unsigned int* gbuf = (unsigned int*)take((size_t)NB * 512 * 4);

  hipMemsetAsync(gbuf, 0, (size_t)NB * 512 * 4, stream);

  hipLaunchKernelGGL(fps_fused_kernel, dim3(NB), dim3(256), 0, stream,
                     pos, posd1, posd2);
  hipLaunchKernelGGL((radius_nbr_kernel<N1, 448>), dim3(NB * K1 / 4), dim3(256), 0, stream,
                     pos, posd1, K1, 4.0f, nbr1, cnt1);
  hipLaunchKernelGGL((sa_conv_kernel<32, 64, 128, true>), dim3(NB * K1), dim3(256), 0, stream,
                     x, pos, posd1, nbr1, cnt1, s1w1, s1b1, s1w2, s1b2,
                     smean, sstd, N1, K1, x1);
  hipLaunchKernelGGL((radius_nbr_kernel<K1, 448>), dim3(NB * K2 / 4), dim3(256), 0, stream,
                     posd1, posd2, K2, 16.0f, nbr2, cnt2);
  hipLaunchKernelGGL((sa_conv_kernel<128, 128, 256, false>), dim3(NB * K2), dim3(256), 0, stream,
                     x1, posd1, posd2, nbr2, cnt2, s2w1, s2b1, s2w2, s2b2,
                     nullptr, nullptr, K1, K2, x2);
  hipLaunchKernelGGL(global_sa_kernel, dim3(NB * 64), dim3(256), 0, stream,
                     x2, posd2, gw1, gb1, gw2, gb2, gbuf);
  hipLaunchKernelGGL(fc_kernel, dim3(NB), dim3(256), 0, stream,
                     gbuf, fw1, fb1, fw2, fb2, (float*)d_out);
}

// Round 5
// 1397.965 us; speedup vs baseline: 1.7624x; 1.2488x over previous
//
#include <hip/hip_runtime.h>
#include <hip/hip_bf16.h>
#include <math.h>

namespace {

constexpr int NB   = 16;     // graphs
constexpr int N1   = 4096;   // points per graph
constexpr int K1   = 1024;   // SA1 centers
constexpr int K2   = 256;    // SA2 centers
constexpr int MAXN = 32;     // max neighbors

__device__ __forceinline__ float sigmoidf_(float x) {
  return 1.0f / (1.0f + __expf(-x));
}

__device__ __forceinline__ float readlane_f(float v, int l) {
  return __int_as_float(__builtin_amdgcn_readlane(__float_as_int(v), l));
}

// ---------------- Farthest-point sampling (fused 2-level) ----------------
// One block (256 threads, 4 waves) per graph. Points staged in LDS, per-thread
// min-distances in registers. Keys packed (f32 dist bits << 32) | ~point_idx
// so a single u64 max implements "max dist, tie -> smallest index".

#define FPS_DPP_STEP(CTRL)                                                     \
  {                                                                            \
    const unsigned olo =                                                       \
        (unsigned)__builtin_amdgcn_update_dpp(0, (int)lo, (CTRL), 0xF, 0xF, true); \
    const unsigned ohi =                                                       \
        (unsigned)__builtin_amdgcn_update_dpp(0, (int)hi, (CTRL), 0xF, 0xF, true); \
    const unsigned long long o = ((unsigned long long)ohi << 32) | olo;        \
    const unsigned long long cur = ((unsigned long long)hi << 32) | lo;        \
    if (o > cur) { lo = olo; hi = ohi; }                                       \
  }

template<int NPT>
__device__ __forceinline__ void fps_level(
    const float* __restrict__ sx, const float* __restrict__ sy,
    const float* __restrict__ sz, int k,
    float* __restrict__ selx, float* __restrict__ sely,
    float* __restrict__ selz,                       // LDS, length k
    unsigned long long (*red)[4]) {
  const int t = threadIdx.x;
  const int lane = t & 63, wave = t >> 6;
  float px[NPT], py[NPT], pz[NPT], mind[NPT];
  unsigned niv[NPT];
  const float c0x = sx[0], c0y = sy[0], c0z = sz[0];
  unsigned long long best = 0;  // identity: dist 0, idx ~0 (never wins)
#pragma unroll
  for (int i = 0; i < NPT; i++) {
    const int p = i * 256 + t;
    niv[i] = ~(unsigned)p;
    px[i] = sx[p]; py[i] = sy[p]; pz[i] = sz[p];
    const float dx = px[i] - c0x, dy = py[i] - c0y, dz = pz[i] - c0z;
    const float d2 = dx * dx + dy * dy + dz * dz;
    mind[i] = d2;
    const unsigned long long cand =
        ((unsigned long long)__float_as_uint(d2) << 32) | niv[i];
    if (cand > best) best = cand;
  }
  if (t == 0) { selx[0] = c0x; sely[0] = c0y; selz[0] = c0z; }
  for (int it = 1; it < k; it++) {
    // ---- wave argmax via DPP: result lands in lane 63 ----
    unsigned lo = (unsigned)best, hi = (unsigned)(best >> 32);
    FPS_DPP_STEP(0x111)  // row_shr:1
    FPS_DPP_STEP(0x112)  // row_shr:2
    FPS_DPP_STEP(0x114)  // row_shr:4
    FPS_DPP_STEP(0x118)  // row_shr:8
    FPS_DPP_STEP(0x142)  // row_bcast:15
    FPS_DPP_STEP(0x143)  // row_bcast:31
    const int par = it & 1;
    if (lane == 63) red[par][wave] = ((unsigned long long)hi << 32) | lo;
    __syncthreads();
    const unsigned long long w0 = red[par][0], w1 = red[par][1];
    const unsigned long long w2 = red[par][2], w3 = red[par][3];
    const unsigned long long m01 = w0 > w1 ? w0 : w1;
    const unsigned long long m23 = w2 > w3 ? w2 : w3;
    const unsigned long long win = m01 > m23 ? m01 : m23;
    const int p = (int)(~(unsigned)win);
    const float nx = sx[p], ny = sy[p], nz = sz[p];
    if (t == 0) { selx[it] = nx; sely[it] = ny; selz[it] = nz; }
    best = 0;
#pragma unroll
    for (int i = 0; i < NPT; i++) {
      const float dx = px[i] - nx, dy = py[i] - ny, dz = pz[i] - nz;
      const float d2 = dx * dx + dy * dy + dz * dz;
      const float m = fminf(mind[i], d2);
      mind[i] = m;
      const unsigned long long cand =
          ((unsigned long long)__float_as_uint(m) << 32) | niv[i];
      if (cand > best) best = cand;
    }
  }
}

#undef FPS_DPP_STEP

__global__ __launch_bounds__(256) void fps_fused_kernel(
    const float* __restrict__ pos, float* __restrict__ posd1,
    float* __restrict__ posd2) {
  __shared__ float sx[N1], sy[N1], sz[N1];       // 48 KiB
  __shared__ float s2x[K1], s2y[K1], s2z[K1];    // 12 KiB (level-1 selections)
  __shared__ float p2x[K2], p2y[K2], p2z[K2];    //  3 KiB (level-2 selections)
  __shared__ __align__(16) unsigned long long red[2][4];
  const int b = blockIdx.x;
  const int t = threadIdx.x;
  const float* pb = pos + (size_t)b * N1 * 3;
  for (int p = t; p < N1; p += 256) {
    sx[p] = pb[p * 3 + 0]; sy[p] = pb[p * 3 + 1]; sz[p] = pb[p * 3 + 2];
  }
  __syncthreads();
  // level 1: 4096 -> 1024 (selections -> s2*)
  fps_level<N1 / 256>(sx, sy, sz, K1, s2x, s2y, s2z, red);
  __syncthreads();
  // level 2: 1024 -> 256 (selections -> p2*)
  fps_level<K1 / 256>(s2x, s2y, s2z, K2, p2x, p2y, p2z, red);
  __syncthreads();
  // bulk write both center lists
  float* o1 = posd1 + (size_t)b * K1 * 3;
  for (int i = t; i < K1; i += 256) {
    o1[i * 3 + 0] = s2x[i]; o1[i * 3 + 1] = s2y[i]; o1[i * 3 + 2] = s2z[i];
  }
  float* o2 = posd2 + (size_t)b * K2 * 3;
  for (int i = t; i < K2; i += 256) {
    o2[i * 3 + 0] = p2x[i]; o2[i * 3 + 1] = p2y[i]; o2[i * 3 + 2] = p2z[i];
  }
}

// ---------------- radius + 32 nearest ----------------
template<int N, int CAP>
__global__ __launch_bounds__(256) void radius_nbr_kernel(
    const float* __restrict__ pts, const float* __restrict__ ctr,
    int K, float r2, int* __restrict__ nbr, int* __restrict__ cnt_out) {
  __shared__ float sx[N], sy[N], sz[N];
  __shared__ float candd[4][CAP];
  __shared__ int   candi[4][CAP];
  const int t = threadIdx.x;
  const int lane = t & 63, wave = t >> 6;
  const int bpg = K / 4;
  const int b = blockIdx.x / bpg;
  const int ci = (blockIdx.x % bpg) * 4 + wave;
  const float* pb = pts + (size_t)b * N * 3;
  for (int p = t; p < N; p += 256) {
    sx[p] = pb[p * 3 + 0]; sy[p] = pb[p * 3 + 1]; sz[p] = pb[p * 3 + 2];
  }
  __syncthreads();
  const size_t cbase = ((size_t)b * K + ci) * 3;
  const float cx = ctr[cbase + 0], cy = ctr[cbase + 1], cz = ctr[cbase + 2];
  int total = 0;
  for (int base = 0; base < N; base += 64) {
    const int p = base + lane;
    const float dx = sx[p] - cx, dy = sy[p] - cy, dz = sz[p] - cz;
    const float d2 = dx * dx + dy * dy + dz * dz;
    const bool pred = d2 <= r2;
    const unsigned long long m = __ballot(pred);
    if (pred) {
      const int slot = total + __popcll(m & ((1ull << lane) - 1ull));
      if (slot < CAP) { candd[wave][slot] = d2; candi[wave][slot] = p; }
    }
    total += __popcll(m);
  }
  if (total > CAP) total = CAP;
  int* nbp = nbr + ((size_t)b * K + ci) * MAXN;
  if (total <= MAXN) {
    if (lane < total) nbp[lane] = candi[wave][lane];
  } else {
    for (int jj = 0; jj < MAXN; jj++) {
      float bvd = INFINITY; int bvi = 0x7fffffff; int bslot = 0;
      for (int s = lane; s < total; s += 64) {
        const float d = candd[wave][s];
        const int i = candi[wave][s];
        if (d < bvd || (d == bvd && i < bvi)) { bvd = d; bvi = i; bslot = s; }
      }
#pragma unroll
      for (int off = 32; off; off >>= 1) {
        const float od = __shfl_xor(bvd, off);
        const int   oi = __shfl_xor(bvi, off);
        const int   os = __shfl_xor(bslot, off);
        if (od < bvd || (od == bvd && oi < bvi)) { bvd = od; bvi = oi; bslot = os; }
      }
      if (lane == 0) { nbp[jj] = bvi; candd[wave][bslot] = INFINITY; }
    }
  }
  if (lane == 0) cnt_out[(size_t)b * K + ci] = (total < MAXN) ? total : MAXN;
}

// ---------------- PointNetConv edge MLP + max aggregation (v2) ----------
// Rows-in-lanes + readlane broadcast: no LDS in the GEMM inner loops.
// Wave w owns rows w*8..w*8+7. Feature row r is held across the wave's lanes
// (lane = feature index, KREG regs). Layer matmuls broadcast feat/h1 values
// with v_readlane (VALU) and stream weight columns coalesced from global
// (L1/L2-resident). Accumulation order over f and h is strictly ascending,
// matching the previous (verified) kernel bit-for-bit.
template<int CIN_T, int H, int COUT, bool SCALE>
__global__ __launch_bounds__(256) void sa_conv_kernel(
    const float* __restrict__ xin, const float* __restrict__ pts,
    const float* __restrict__ ctr, const int* __restrict__ nbr,
    const int* __restrict__ cnt,
    const float* __restrict__ w1, const float* __restrict__ b1,
    const float* __restrict__ w2, const float* __restrict__ b2,
    const float* __restrict__ smean, const float* __restrict__ sstd,
    int N, int K, float* __restrict__ xout) {
  constexpr int FIN  = CIN_T + 3;
  constexpr int KREG = (FIN + 63) / 64;   // feat regs per row per lane
  constexpr int HREG = H / 64;            // hidden regs per lane
  constexpr int CREG = COUT / 64;         // output regs per lane
  constexpr int RPW  = MAXN / 4;          // 8 rows per wave
  __shared__ float part[4][COUT];
  const int t = threadIdx.x, lane = t & 63, wave = t >> 6;
  const int bk = blockIdx.x;
  const int b = bk / K;
  const int V = cnt[bk];
  const int* nb = nbr + (size_t)bk * MAXN;
  const float ctrx = ctr[(size_t)bk * 3 + 0];
  const float ctry = ctr[(size_t)bk * 3 + 1];
  const float ctrz = ctr[(size_t)bk * 3 + 2];
  // per-lane normalization params (conv1 only)
  float sm = 0.0f, sd = 1.0f;
  if (SCALE && lane < CIN_T) { sm = smean[lane]; sd = sstd[lane]; }
  // ---- gather feature rows into lane registers (coalesced) ----
  float fr[RPW][KREG];
#pragma unroll
  for (int r = 0; r < RPW; r++) {
    const int j = wave * RPW + r;
    const int p = (j < V) ? nb[j] : nb[0];   // clamp invalid rows to a safe idx
#pragma unroll
    for (int k2 = 0; k2 < KREG; k2++) {
      const int f = k2 * 64 + lane;
      float v = 0.0f;
      if (f < CIN_T) {
        v = xin[((size_t)b * N + p) * CIN_T + f];
        if constexpr (SCALE) v = (v - sm) / sd;
      } else if (f < FIN) {
        const int d = f - CIN_T;
        const float pv = pts[((size_t)b * N + p) * 3 + d];
        v = pv - (d == 0 ? ctrx : (d == 1 ? ctry : ctrz));
      }
      fr[r][k2] = v;
    }
  }
  // ---- layer 1: h = sigmoid(feat @ W1 + b1), h index = lane (+64k) ----
  float hh[RPW][HREG];
  {
    float acc[RPW][HREG];
#pragma unroll
    for (int r = 0; r < RPW; r++)
#pragma unroll
      for (int hk = 0; hk < HREG; hk++) acc[r][hk] = 0.0f;
#pragma unroll
    for (int k2 = 0; k2 < KREG; k2++) {
      const int lim = (FIN - k2 * 64) < 64 ? (FIN - k2 * 64) : 64;
      for (int fl = 0; fl < lim; fl++) {     // f ascending
        const int f = k2 * 64 + fl;
        float wv[HREG];
#pragma unroll
        for (int hk = 0; hk < HREG; hk++) wv[hk] = w1[(size_t)f * H + hk * 64 + lane];
#pragma unroll
        for (int r = 0; r < RPW; r++) {
          const float s = readlane_f(fr[r][k2], fl);
#pragma unroll
          for (int hk = 0; hk < HREG; hk++) acc[r][hk] = fmaf(s, wv[hk], acc[r][hk]);
        }
      }
    }
#pragma unroll
    for (int hk = 0; hk < HREG; hk++) {
      const float bb = b1[hk * 64 + lane];
#pragma unroll
      for (int r = 0; r < RPW; r++) hh[r][hk] = sigmoidf_(acc[r][hk] + bb);
    }
  }
  // ---- layer 2: out = h @ W2 (h ascending), then masked max over rows ----
  float acc2[RPW][CREG];
#pragma unroll
  for (int r = 0; r < RPW; r++)
#pragma unroll
    for (int ck = 0; ck < CREG; ck++) acc2[r][ck] = 0.0f;
#pragma unroll
  for (int hk = 0; hk < HREG; hk++) {
    for (int hl = 0; hl < 64; hl++) {        // h ascending
      const int h = hk * 64 + hl;
      float wv[CREG];
#pragma unroll
      for (int ck = 0; ck < CREG; ck++) wv[ck] = w2[(size_t)h * COUT + ck * 64 + lane];
#pragma unroll
      for (int r = 0; r < RPW; r++) {
        const float s = readlane_f(hh[r][hk], hl);
#pragma unroll
        for (int ck = 0; ck < CREG; ck++) acc2[r][ck] = fmaf(s, wv[ck], acc2[r][ck]);
      }
    }
  }
  float m[CREG];
#pragma unroll
  for (int ck = 0; ck < CREG; ck++) m[ck] = -INFINITY;
#pragma unroll
  for (int r = 0; r < RPW; r++) {
    if (wave * RPW + r < V) {
#pragma unroll
      for (int ck = 0; ck < CREG; ck++) m[ck] = fmaxf(m[ck], acc2[r][ck]);
    }
  }
#pragma unroll
  for (int ck = 0; ck < CREG; ck++) part[wave][ck * 64 + lane] = m[ck];
  __syncthreads();
  if (t < COUT) {
    const float mm = fmaxf(fmaxf(part[0][t], part[1][t]),
                           fmaxf(part[2][t], part[3][t]));
    const float o = mm + b2[t];
    xout[(size_t)bk * COUT + t] = o > 0.0f ? o : 0.0f;
  }
}

// ---------------- Global SA: MLP(259->256->512) + relu + max pool ----------
__global__ __launch_bounds__(256) void global_sa_kernel(
    const float* __restrict__ x2, const float* __restrict__ posd2,
    const float* __restrict__ gw1, const float* __restrict__ gb1,
    const float* __restrict__ gw2, const float* __restrict__ gb2,
    unsigned int* __restrict__ gout) {  // [B][512] as float bits (relu >= 0)
  __shared__ float fin[4][259];
  __shared__ float s[4][256];
  const int t = threadIdx.x;
  const int blk = blockIdx.x;
  const int b = blk / 64;
  const int p0 = (blk % 64) * 4;
  for (int item = t; item < 4 * 259; item += 256) {
    const int p = item / 259, f = item - p * 259;
    const float v = (f < 256)
        ? x2[((size_t)b * 256 + p0 + p) * 256 + f]
        : posd2[((size_t)b * 256 + p0 + p) * 3 + (f - 256)];
    fin[p][f] = v;
  }
  __syncthreads();
  float acc[4] = {0.f, 0.f, 0.f, 0.f};
  for (int f = 0; f < 259; f++) {
    const float w = gw1[f * 256 + t];
#pragma unroll
    for (int p = 0; p < 4; p++) acc[p] = fmaf(fin[p][f], w, acc[p]);
  }
  const float bb = gb1[t];
#pragma unroll
  for (int p = 0; p < 4; p++) s[p][t] = sigmoidf_(acc[p] + bb);
  __syncthreads();
  float a0[4] = {0.f, 0.f, 0.f, 0.f}, a1[4] = {0.f, 0.f, 0.f, 0.f};
  for (int h = 0; h < 256; h++) {
    const float w0 = gw2[h * 512 + t];
    const float w1v = gw2[h * 512 + t + 256];
#pragma unroll
    for (int p = 0; p < 4; p++) {
      a0[p] = fmaf(s[p][h], w0, a0[p]);
      a1[p] = fmaf(s[p][h], w1v, a1[p]);
    }
  }
  const float b0 = gb2[t], b1v = gb2[t + 256];
  float m0 = 0.0f, m1 = 0.0f;  // relu floor
#pragma unroll
  for (int p = 0; p < 4; p++) {
    m0 = fmaxf(m0, fmaxf(a0[p] + b0, 0.0f));
    m1 = fmaxf(m1, fmaxf(a1[p] + b1v, 0.0f));
  }
  atomicMax(&gout[b * 512 + t], __float_as_uint(m0));
  atomicMax(&gout[b * 512 + t + 256], __float_as_uint(m1));
}

// ---------------- Final FC head (float32 output) ----------------
__global__ __launch_bounds__(256) void fc_kernel(
    const unsigned int* __restrict__ g,
    const float* __restrict__ fw1, const float* __restrict__ fb1,
    const float* __restrict__ fw2, const float* __restrict__ fb2,
    float* __restrict__ out) {
  __shared__ float gv[512];
  __shared__ float s[256];
  const int b = blockIdx.x, t = threadIdx.x;
  gv[t] = __uint_as_float(g[b * 512 + t]);
  gv[t + 256] = __uint_as_float(g[b * 512 + t + 256]);
  __syncthreads();
  float acc = 0.0f;
  for (int h = 0; h < 512; h++) acc = fmaf(gv[h], fw1[h * 256 + t], acc);
  s[t] = sigmoidf_(acc + fb1[t]);
  __syncthreads();
  if (t < 128) {
    float a2 = 0.0f;
    for (int h = 0; h < 256; h++) a2 = fmaf(s[h], fw2[h * 128 + t], a2);
    const float o = a2 + fb2[t];
    out[b * 128 + t] = o > 0.0f ? o : 0.0f;
  }
}

}  // namespace

extern "C" void kernel_launch(void* const* d_in, const int* in_sizes, int n_in,
                              void* d_out, int out_size, void* d_ws, size_t ws_size,
                              hipStream_t stream) {
  (void)in_sizes; (void)n_in; (void)out_size; (void)ws_size;
  const float* x     = (const float*)d_in[0];
  const float* pos   = (const float*)d_in[1];
  // d_in[2] = batch (int64) — sorted, equal-sized graphs, unused
  const float* smean = (const float*)d_in[3];
  const float* sstd  = (const float*)d_in[4];
  const float* s1w1  = (const float*)d_in[5];
  const float* s1b1  = (const float*)d_in[6];
  const float* s1w2  = (const float*)d_in[7];
  const float* s1b2  = (const float*)d_in[8];
  const float* s2w1  = (const float*)d_in[9];
  const float* s2b1  = (const float*)d_in[10];
  const float* s2w2  = (const float*)d_in[11];
  const float* s2b2  = (const float*)d_in[12];
  const float* gw1   = (const float*)d_in[13];
  const float* gb1   = (const float*)d_in[14];
  const float* gw2   = (const float*)d_in[15];
  const float* gb2   = (const float*)d_in[16];
  const float* fw1   = (const float*)d_in[17];
  const float* fb1   = (const float*)d_in[18];
  const float* fw2   = (const float*)d_in[19];
  const float* fb2   = (const float*)d_in[20];

  char* ws = (char*)d_ws;
  size_t off = 0;
  auto take = [&](size_t bytes) -> char* {
    char* p = ws + off;
    off = (off + bytes + 255) & ~(size_t)255;
    return p;
  };
  float* posd1       = (float*)take((size_t)NB * K1 * 3 * 4);
  int*   nbr1        = (int*)take((size_t)NB * K1 * MAXN * 4);
  int*   cnt1        = (int*)take((size_t)NB * K1 * 4);
  float* x1          = (float*)take((size_t)NB * K1 * 128 * 4);
  float* posd2       = (float*)take((size_t)NB * K2 * 3 * 4);
  int*   nbr2        = (int*)take((size_t)NB * K2 * MAXN * 4);
  int*   cnt2        = (int*)take((size_t)NB * K2 * 4);
  float* x2          = (float*)take((size_t)NB * K2 * 256 * 4);
  unsigned int* gbuf = (unsigned int*)take((size_t)NB * 512 * 4);

  hipMemsetAsync(gbuf, 0, (size_t)NB * 512 * 4, stream);

  hipLaunchKernelGGL(fps_fused_kernel, dim3(NB), dim3(256), 0, stream,
                     pos, posd1, posd2);
  hipLaunchKernelGGL((radius_nbr_kernel<N1, 448>), dim3(NB * K1 / 4), dim3(256), 0, stream,
                     pos, posd1, K1, 4.0f, nbr1, cnt1);
  hipLaunchKernelGGL((sa_conv_kernel<32, 64, 128, true>), dim3(NB * K1), dim3(256), 0, stream,
                     x, pos, posd1, nbr1, cnt1, s1w1, s1b1, s1w2, s1b2,
                     smean, sstd, N1, K1, x1);
  hipLaunchKernelGGL((radius_nbr_kernel<K1, 448>), dim3(NB * K2 / 4), dim3(256), 0, stream,
                     posd1, posd2, K2, 16.0f, nbr2, cnt2);
  hipLaunchKernelGGL((sa_conv_kernel<128, 128, 256, false>), dim3(NB * K2), dim3(256), 0, stream,
                     x1, posd1, posd2, nbr2, cnt2, s2w1, s2b1, s2w2, s2b2,
                     nullptr, nullptr, K1, K2, x2);
  hipLaunchKernelGGL(global_sa_kernel, dim3(NB * 64), dim3(256), 0, stream,
                     x2, posd2, gw1, gb1, gw2, gb2, gbuf);
  hipLaunchKernelGGL(fc_kernel, dim3(NB), dim3(256), 0, stream,
                     gbuf, fw1, fb1, fw2, fb2, (float*)d_out);
}